// Round 2
// 8280.250 us; speedup vs baseline: 1.1250x; 1.1250x over previous
//
#include <hip/hip_runtime.h>
#include <hip/hip_bf16.h>

// GRU scan B=256, S=512, I=512, H=1024 + Linear(H,1).
// R5 == R4 resubmit (R4 bench was an infra failure, no signal).
// R4: attack straggler-amplified lockstep stall (85% of step time).
//   R3 post-mortem: 17.8 us/step, MfmaUtil 5.4%, VALUBusy 7.5% -> ~85% stall.
//   FETCH_SIZE 2.135 GB = 8 x sizeof(x): x thrashes L3 and streams from HBM
//   every step; HBM-latency jitter inside the 64-block lockstep is maxed
//   across the group each step.
//   R4 changes:
//   - x converted once to bf16 (xb, 128 MB) in prep when ws allows: x-phase
//     loads halve, footprint becomes L3-resident, pack VALU leaves the loop.
//     Fallback (template<XB=0>) keeps the fp32 path if ws_size < 145 MB.
//   - Per-wave waits: wave w consumes h cols [256w,256w+256) = producers
//     [16w,16w+16) only; spin on those 16 flags, no block-wide barrier.
//     WAR safety on the ping-pong: union of the 4 waves' producer sets is
//     all 64 blocks, and barrier A (pre-store) joins the waves, so step-t+1
//     h stores still wait for every block to finish step t.
//   - Packed h stores: epilogue -> h32s (LDS); one 8B agent store per lane
//     (was 4x2B scattered) -> faster vmcnt drain before the flag publish.

#define B_  256
#define S_  512
#define I_  512
#define H_  1024
#define GSIZE 64   // blocks per mt-group

typedef __bf16 bf16x8 __attribute__((ext_vector_type(8)));
typedef float  f32x4  __attribute__((ext_vector_type(4)));

union U16x8 { int4 i; bf16x8 b; unsigned short s[8]; unsigned u[4]; };

__device__ __forceinline__ unsigned pack2bf(float lo, float hi) {
    union { float f; unsigned u; } a, b;
    a.f = lo; b.f = hi;
    return __builtin_amdgcn_perm(b.u + 0x8000u, a.u + 0x8000u, 0x07060302u);
}
__device__ __forceinline__ bf16x8 ldb(const unsigned short* p) {
    U16x8 u; u.i = *(const int4*)p; return u.b;
}
// device-scope (sc1) 16B h load as two relaxed 8B atomic loads (pipelined,
// no per-load waitcnt since relaxed)
__device__ __forceinline__ bf16x8 ldh_dev(const unsigned long long* p) {
    unsigned long long lo = __hip_atomic_load(p,     __ATOMIC_RELAXED, __HIP_MEMORY_SCOPE_AGENT);
    unsigned long long hi = __hip_atomic_load(p + 1, __ATOMIC_RELAXED, __HIP_MEMORY_SCOPE_AGENT);
    union { unsigned long long q[2]; bf16x8 b; } u;
    u.q[0] = lo; u.q[1] = hi; return u.b;
}

// -------- prep: fp32->bf16 weight (+x) convert, zero h0 + flags --------
__global__ void prep_kernel(const float* __restrict__ wh, const float* __restrict__ wi,
                            const float* __restrict__ x,
                            unsigned* __restrict__ hbA_u, unsigned* __restrict__ whb_u,
                            unsigned* __restrict__ wib_u, unsigned* __restrict__ flags,
                            unsigned* __restrict__ xb_u) {
    int idx = blockIdx.x * blockDim.x + threadIdx.x;
    int stride = gridDim.x * blockDim.x;
    const float2* wh2 = (const float2*)wh;
    const float2* wi2 = (const float2*)wi;
    for (int i = idx; i < 3 * H_ * H_ / 2; i += stride) { float2 v = wh2[i]; whb_u[i] = pack2bf(v.x, v.y); }
    for (int i = idx; i < 3 * H_ * I_ / 2; i += stride) { float2 v = wi2[i]; wib_u[i] = pack2bf(v.x, v.y); }
    for (int i = idx; i < B_ * H_ / 2; i += stride) hbA_u[i] = 0u;
    if (idx < 256 * 16) flags[idx] = 0u;   // 256 blocks x 64B-padded flag
    if (xb_u) {
        const float2* x2 = (const float2*)x;
        const int n = B_ * S_ * I_ / 2;    // 33.5M u32 outputs
        for (int i = idx; i < n; i += stride) { float2 v = x2[i]; xb_u[i] = pack2bf(v.x, v.y); }
    }
}

// -------- persistent GRU scan --------
template<int XB>
__global__ __launch_bounds__(256, 1) void gru_persistent(
    const float* __restrict__ x,
    const unsigned short* __restrict__ xbp,
    const unsigned short* __restrict__ whb,
    const unsigned short* __restrict__ wib,
    const float* __restrict__ bi,
    const float* __restrict__ bn,
    unsigned short* __restrict__ hbufA,
    unsigned short* __restrict__ hbufB,
    float* __restrict__ h32g,
    unsigned* __restrict__ flags)   // flags[blk*16]: steps completed by blk
{
    __shared__ float partial[4 * 3 * 16 * 68];
    __shared__ float h32s[64 * 17];

    const int tid  = threadIdx.x;
    const int w    = tid >> 6;
    const int lane = tid & 63;
    const int col  = lane & 15;
    const int quad = lane >> 4;

    const int hblk = blockIdx.x & 63;
    const int mt   = blockIdx.x >> 6;
    const int k0   = hblk << 4;
    const int b0   = mt << 6;
    const int kwh  = w << 8;
    const int kwi  = w << 7;

    // ---- persistent B fragments (loaded once, normal cached loads) ----
    bf16x8 Bh[3][8];
    bf16x8 Bx[3][4];
    #pragma unroll
    for (int g = 0; g < 3; ++g) {
        const unsigned short* bh = whb + ((size_t)(g * H_ + k0 + col)) * H_ + kwh + (quad << 3);
        #pragma unroll
        for (int kk = 0; kk < 8; ++kk) Bh[g][kk] = ldb(bh + kk * 32);
        const unsigned short* bx = wib + ((size_t)(g * H_ + k0 + col)) * I_ + kwi + (quad << 3);
        #pragma unroll
        for (int kk = 0; kk < 4; ++kk) Bx[g][kk] = ldb(bx + kk * 32);
    }

    const int hcol = k0 + col;
    const float bir = bi[hcol], biz = bi[H_ + hcol], bia = bi[2 * H_ + hcol], bnv = bn[hcol];

    for (int i = tid; i < 64 * 17; i += 256) h32s[i] = 0.f;
    __syncthreads();

    unsigned* myflag = flags + blockIdx.x * 16;
    const unsigned* grpflags = flags + (mt * 64) * 16;

    const f32x4 zero4 = {0.f, 0.f, 0.f, 0.f};

    for (int t = 0; t < S_; ++t) {
        f32x4 acc[4][4];   // [mi][0=r,1=z,2=ia,3=ha]
        #pragma unroll
        for (int mi = 0; mi < 4; ++mi)
            #pragma unroll
            for (int j = 0; j < 4; ++j) acc[mi][j] = zero4;

        // ---- x-phase (independent of h; overlaps group skew) ----
        if constexpr (XB) {
            const unsigned short* xbase = xbp + ((size_t)(b0 + col) * S_ + (size_t)t) * I_ + kwi + (quad << 3);
            #pragma unroll
            for (int kk = 0; kk < 4; ++kk) {
                #pragma unroll
                for (int mi = 0; mi < 4; ++mi) {
                    bf16x8 a = ldb(xbase + (size_t)mi * 16 * S_ * I_ + kk * 32);
                    acc[mi][0] = __builtin_amdgcn_mfma_f32_16x16x32_bf16(a, Bx[0][kk], acc[mi][0], 0, 0, 0);
                    acc[mi][1] = __builtin_amdgcn_mfma_f32_16x16x32_bf16(a, Bx[1][kk], acc[mi][1], 0, 0, 0);
                    acc[mi][2] = __builtin_amdgcn_mfma_f32_16x16x32_bf16(a, Bx[2][kk], acc[mi][2], 0, 0, 0);
                }
            }
        } else {
            const float* xbase = x + ((size_t)(b0 + col) * S_ + (size_t)t) * I_ + kwi + (quad << 3);
            #pragma unroll
            for (int kk = 0; kk < 4; ++kk) {
                #pragma unroll
                for (int mi = 0; mi < 4; ++mi) {
                    const float* p = xbase + (size_t)mi * 16 * S_ * I_ + kk * 32;
                    float4 f0 = *(const float4*)p;
                    float4 f1 = *(const float4*)(p + 4);
                    U16x8 u;
                    u.u[0] = pack2bf(f0.x, f0.y);
                    u.u[1] = pack2bf(f0.z, f0.w);
                    u.u[2] = pack2bf(f1.x, f1.y);
                    u.u[3] = pack2bf(f1.z, f1.w);
                    bf16x8 a = u.b;
                    acc[mi][0] = __builtin_amdgcn_mfma_f32_16x16x32_bf16(a, Bx[0][kk], acc[mi][0], 0, 0, 0);
                    acc[mi][1] = __builtin_amdgcn_mfma_f32_16x16x32_bf16(a, Bx[1][kk], acc[mi][1], 0, 0, 0);
                    acc[mi][2] = __builtin_amdgcn_mfma_f32_16x16x32_bf16(a, Bx[2][kk], acc[mi][2], 0, 0, 0);
                }
            }
        }

        // ---- per-wave wait: wave w consumes h cols [256w,256w+256), i.e.
        //      producers [16w,16w+16). Spin on just those 16 flags. ----
        if (t > 0) {
            if (lane < 16) {
                const unsigned* fp = grpflags + (((w << 4) + lane) << 4);
                while (__hip_atomic_load(fp, __ATOMIC_RELAXED, __HIP_MEMORY_SCOPE_AGENT) < (unsigned)t)
                    __builtin_amdgcn_s_sleep(1);
            }
            // compiler-only fence: keep the h loads below the spin
            asm volatile("" ::: "memory");
        }

        // ---- h-phase: device-scope loads bypass stale per-XCD L2 ----
        const unsigned short* hcur = (t & 1) ? hbufB : hbufA;
        const unsigned short* hrow = hcur + (size_t)(b0 + col) * H_ + kwh + (quad << 3);
        #pragma unroll
        for (int kk = 0; kk < 8; ++kk) {
            #pragma unroll
            for (int mi = 0; mi < 4; ++mi) {
                bf16x8 a = ldh_dev((const unsigned long long*)(hrow + (size_t)mi * 16 * H_ + kk * 32));
                acc[mi][0] = __builtin_amdgcn_mfma_f32_16x16x32_bf16(a, Bh[0][kk], acc[mi][0], 0, 0, 0);
                acc[mi][1] = __builtin_amdgcn_mfma_f32_16x16x32_bf16(a, Bh[1][kk], acc[mi][1], 0, 0, 0);
                acc[mi][3] = __builtin_amdgcn_mfma_f32_16x16x32_bf16(a, Bh[2][kk], acc[mi][3], 0, 0, 0);
            }
        }

        // ---- publish partials for the 3 m-slices this wave doesn't own ----
        #pragma unroll
        for (int mi = 0; mi < 4; ++mi) {
            if (mi == w) continue;
            int slot = mi - (mi > w ? 1 : 0);
            float* dst = partial + (size_t)((w * 3 + slot) * 16) * 68;
            #pragma unroll
            for (int j = 0; j < 4; ++j)
                #pragma unroll
                for (int r = 0; r < 4; ++r)
                    dst[((quad << 2) + r) * 68 + j * 16 + col] = acc[mi][j][r];
        }
        __syncthreads();   // A: partials ready; also joins the 4 per-wave
                           // waits -> all 64 group flags >= t before any
                           // global h store below (ping-pong WAR safety)

        // ---- epilogue: wave w handles batch rows [w*16, w*16+16) ----
        #pragma unroll
        for (int r = 0; r < 4; ++r) {
            float sr = 0.f, sz = 0.f, sia = 0.f, sha = 0.f;
            #pragma unroll
            for (int mi = 0; mi < 4; ++mi)
                if (mi == w) { sr = acc[mi][0][r]; sz = acc[mi][1][r]; sia = acc[mi][2][r]; sha = acc[mi][3][r]; }
            #pragma unroll
            for (int p = 0; p < 4; ++p) {
                if (p == w) continue;
                int slot = w - (w > p ? 1 : 0);
                const float* src = partial + (size_t)(((p * 3 + slot) * 16 + (quad << 2) + r)) * 68 + col;
                sr  += src[0];
                sz  += src[16];
                sia += src[32];
                sha += src[48];
            }
            float rg = 1.f / (1.f + __expf(-(sr + bir)));
            float zg = 1.f / (1.f + __expf(-(sz + biz)));
            float pa = sia + bia + rg * (sha + bnv);
            float e2 = __expf(2.f * pa);
            float ng = 1.f - 2.f / (e2 + 1.f);
            int m = (w << 4) + (quad << 2) + r;
            float hold = h32s[m * 17 + col];
            float hnew = ng + zg * (hold - ng);
            h32s[m * 17 + col] = hnew;
            if (t == S_ - 1) h32g[(size_t)(b0 + m) * H_ + k0 + col] = hnew;
        }
        __syncthreads();   // B: h32s complete

        // ---- packed h store: one 8B device-scope store per lane ----
        {
            unsigned short* hnext = (t & 1) ? hbufA : hbufB;
            const int m  = tid >> 2;
            const int c4 = (tid & 3) << 2;
            const float* hp = h32s + m * 17 + c4;
            unsigned long long pkt = (unsigned long long)pack2bf(hp[0], hp[1])
                                   | ((unsigned long long)pack2bf(hp[2], hp[3]) << 32);
            __hip_atomic_store((unsigned long long*)(hnext + (size_t)(b0 + m) * H_ + k0 + c4),
                               pkt, __ATOMIC_RELAXED, __HIP_MEMORY_SCOPE_AGENT);
        }
        __syncthreads();   // C: barrier drains vmcnt(0) -> h stores are at
                           // the coherence point before the flag publish

        if (tid == 0)
            __hip_atomic_store(myflag, (unsigned)(t + 1), __ATOMIC_RELAXED, __HIP_MEMORY_SCOPE_AGENT);
    }
}

// -------- final linear: energies[b] = h_T[b] . wl + bl --------
__global__ __launch_bounds__(256) void final_kernel(const float* __restrict__ h32,
                                                    const float* __restrict__ wl,
                                                    const float* __restrict__ bl,
                                                    float* __restrict__ out) {
    const int b = blockIdx.x;
    float s = 0.f;
    for (int k = threadIdx.x; k < H_; k += 256)
        s += h32[((size_t)b << 10) + k] * wl[k];
    #pragma unroll
    for (int off = 32; off > 0; off >>= 1)
        s += __shfl_down(s, off, 64);
    __shared__ float red[4];
    const int wave = threadIdx.x >> 6;
    const int lane = threadIdx.x & 63;
    if (lane == 0) red[wave] = s;
    __syncthreads();
    if (threadIdx.x == 0)
        out[b] = red[0] + red[1] + red[2] + red[3] + bl[0];
}

extern "C" void kernel_launch(void* const* d_in, const int* in_sizes, int n_in,
                              void* d_out, int out_size, void* d_ws, size_t ws_size,
                              hipStream_t stream) {
    const float* x  = (const float*)d_in[0];
    const float* wi = (const float*)d_in[1];
    const float* wh = (const float*)d_in[2];
    const float* bi = (const float*)d_in[3];
    const float* bn = (const float*)d_in[4];
    const float* wl = (const float*)d_in[5];
    const float* bl = (const float*)d_in[6];
    float* out = (float*)d_out;

    // Workspace layout:
    // [0,1M)      h32g fp32 (256x1024)      [1M,1.5M)  hbA bf16
    // [1.5M,2M)   hbB bf16                  [2M,8M)    whb bf16 (3072x1024)
    // [8M,11M)    wib bf16 (3072x512)       [11M,+16K) flags (256 x 64B)
    // [16M,144M)  xb bf16 (256x512x512)     -- only if ws_size >= 145M
    char* ws = (char*)d_ws;
    float*          h32g  = (float*)ws;
    unsigned short* hbA   = (unsigned short*)(ws + (1u << 20));
    unsigned short* hbB   = (unsigned short*)(ws + (1u << 20) + (512u << 10));
    unsigned short* whb   = (unsigned short*)(ws + (2u << 20));
    unsigned short* wib   = (unsigned short*)(ws + (8u << 20));
    unsigned*       flags = (unsigned*)(ws + (11u << 20));
    const bool use_xb = ws_size >= (145ull << 20);
    unsigned short* xbw = use_xb ? (unsigned short*)(ws + (16ull << 20)) : nullptr;

    prep_kernel<<<1024, 256, 0, stream>>>(wh, wi, x, (unsigned*)hbA, (unsigned*)whb,
                                          (unsigned*)wib, flags, (unsigned*)xbw);
    if (use_xb)
        gru_persistent<1><<<256, 256, 0, stream>>>(x, xbw, whb, wib, bi, bn, hbA, hbB, h32g, flags);
    else
        gru_persistent<0><<<256, 256, 0, stream>>>(x, nullptr, whb, wib, bi, bn, hbA, hbB, h32g, flags);
    final_kernel<<<B_, 256, 0, stream>>>(h32g, wl, bl, out);
}

// Round 4
// 7889.183 us; speedup vs baseline: 1.1808x; 1.0496x over previous
//
#include <hip/hip_runtime.h>
#include <hip/hip_bf16.h>

// GRU scan B=256, S=512, I=512, H=1024 + Linear(H,1).
// R7 == R6 with compile fix (__builtin_nontemporal_load needs a clang
// ext_vector_type pointer, not HIP's float4 struct).
// R6: per-wave flags + barrier-C removal + h-load double-buffer + robust fallback.
//   R5 post-mortem: Round1 pod ran XB=1 (VGPR 168, FETCH 611MB, WRITE 49MB,
//   11.1 us/step = theory confirmed). Round2 pod ran XB=0 fallback (VGPR 172,
//   WRITE 267264KB byte-identical to R3 = fp32 x thrashes L3, ws_size<145MB
//   on that pod). Residual on fast path: ~90% stall at 1 wave/SIMD, phase-
//   serialized critical path ending in barrier C's block-wide vmcnt drain.
//   R6 changes:
//   - flags become per-(block,wave): wave w stores exactly its own 16 rows,
//     drains with wave-local s_waitcnt vmcnt(0), publishes its own flag.
//     Barrier C deleted. Consumer wave spins on 64 flags (16 blocks x 4
//     waves), one per lane.
//     WAR safety: barrier A joins the 4 waves (spin-union = all 64 group
//     blocks >= t) before any global h store; barrier B separates partial-
//     reads(t) from partial-publishes(t+1).  B is LOAD-BEARING for both.
//   - h-phase: explicit 2-deep kk prefetch (static indices only).
//   - XB=0 fallback: nontemporal fp32 x loads (x has no cross-step reuse;
//     stop the 256MB stream evicting h/weights from L3).
//   - xb threshold 140MB (flags shrunk, xb at 12MB offset).

#define B_  256
#define S_  512
#define I_  512
#define H_  1024

typedef __bf16 bf16x8 __attribute__((ext_vector_type(8)));
typedef float  f32x4  __attribute__((ext_vector_type(4)));
typedef float  f32x4v __attribute__((ext_vector_type(4)));   // for nontemporal builtin

union U16x8 { int4 i; bf16x8 b; unsigned short s[8]; unsigned u[4]; };

__device__ __forceinline__ unsigned pack2bf(float lo, float hi) {
    union { float f; unsigned u; } a, b;
    a.f = lo; b.f = hi;
    return __builtin_amdgcn_perm(b.u + 0x8000u, a.u + 0x8000u, 0x07060302u);
}
__device__ __forceinline__ bf16x8 ldb(const unsigned short* p) {
    U16x8 u; u.i = *(const int4*)p; return u.b;
}
// device-scope (sc1) 16B h load as two relaxed 8B atomic loads (pipelined,
// no per-load waitcnt since relaxed)
__device__ __forceinline__ bf16x8 ldh_dev(const unsigned long long* p) {
    unsigned long long lo = __hip_atomic_load(p,     __ATOMIC_RELAXED, __HIP_MEMORY_SCOPE_AGENT);
    unsigned long long hi = __hip_atomic_load(p + 1, __ATOMIC_RELAXED, __HIP_MEMORY_SCOPE_AGENT);
    union { unsigned long long q[2]; bf16x8 b; } u;
    u.q[0] = lo; u.q[1] = hi; return u.b;
}

// -------- prep: fp32->bf16 weight (+x) convert, zero h0 + flags --------
__global__ void prep_kernel(const float* __restrict__ wh, const float* __restrict__ wi,
                            const float* __restrict__ x,
                            unsigned* __restrict__ hbA_u, unsigned* __restrict__ whb_u,
                            unsigned* __restrict__ wib_u, unsigned* __restrict__ flags,
                            unsigned* __restrict__ xb_u) {
    int idx = blockIdx.x * blockDim.x + threadIdx.x;
    int stride = gridDim.x * blockDim.x;
    const float2* wh2 = (const float2*)wh;
    const float2* wi2 = (const float2*)wi;
    for (int i = idx; i < 3 * H_ * H_ / 2; i += stride) { float2 v = wh2[i]; whb_u[i] = pack2bf(v.x, v.y); }
    for (int i = idx; i < 3 * H_ * I_ / 2; i += stride) { float2 v = wi2[i]; wib_u[i] = pack2bf(v.x, v.y); }
    for (int i = idx; i < B_ * H_ / 2; i += stride) hbA_u[i] = 0u;
    if (idx < 256 * 4 * 16) flags[idx] = 0u;   // 256 blocks x 4 waves x 64B
    if (xb_u) {
        const float2* x2 = (const float2*)x;
        const int n = B_ * S_ * I_ / 2;
        for (int i = idx; i < n; i += stride) { float2 v = x2[i]; xb_u[i] = pack2bf(v.x, v.y); }
    }
}

// -------- persistent GRU scan --------
template<int XB>
__global__ __launch_bounds__(256, 1) void gru_persistent(
    const float* __restrict__ x,
    const unsigned short* __restrict__ xbp,
    const unsigned short* __restrict__ whb,
    const unsigned short* __restrict__ wib,
    const float* __restrict__ bi,
    const float* __restrict__ bn,
    unsigned short* __restrict__ hbufA,
    unsigned short* __restrict__ hbufB,
    float* __restrict__ h32g,
    unsigned* __restrict__ flags)   // flags[(blk*4+w)*16]: steps done by (blk,wave)
{
    __shared__ float partial[4 * 3 * 16 * 68];
    __shared__ float h32s[64 * 17];

    const int tid  = threadIdx.x;
    const int w    = tid >> 6;
    const int lane = tid & 63;
    const int col  = lane & 15;
    const int quad = lane >> 4;

    const int hblk = blockIdx.x & 63;
    const int mt   = blockIdx.x >> 6;
    const int k0   = hblk << 4;
    const int b0   = mt << 6;
    const int kwh  = w << 8;
    const int kwi  = w << 7;

    // ---- persistent B fragments (loaded once, normal cached loads) ----
    bf16x8 Bh[3][8];
    bf16x8 Bx[3][4];
    #pragma unroll
    for (int g = 0; g < 3; ++g) {
        const unsigned short* bh = whb + ((size_t)(g * H_ + k0 + col)) * H_ + kwh + (quad << 3);
        #pragma unroll
        for (int kk = 0; kk < 8; ++kk) Bh[g][kk] = ldb(bh + kk * 32);
        const unsigned short* bx = wib + ((size_t)(g * H_ + k0 + col)) * I_ + kwi + (quad << 3);
        #pragma unroll
        for (int kk = 0; kk < 4; ++kk) Bx[g][kk] = ldb(bx + kk * 32);
    }

    const int hcol = k0 + col;
    const float bir = bi[hcol], biz = bi[H_ + hcol], bia = bi[2 * H_ + hcol], bnv = bn[hcol];

    for (int i = tid; i < 64 * 17; i += 256) h32s[i] = 0.f;
    __syncthreads();

    // producer flag: this block, this wave
    unsigned* myflag = flags + (((blockIdx.x << 2) + w) << 4);
    // consumer: wave w's h cols [256w,+256) come from group blocks
    // [16w,16w+16), all 4 waves each -> 64 flags, one per lane
    const unsigned* spin_fp = flags +
        ((((mt << 6) + (w << 4) + (lane >> 2)) * 4 + (lane & 3)) << 4);

    const f32x4 zero4 = {0.f, 0.f, 0.f, 0.f};

    for (int t = 0; t < S_; ++t) {
        f32x4 acc[4][4];   // [mi][0=r,1=z,2=ia,3=ha]
        #pragma unroll
        for (int mi = 0; mi < 4; ++mi)
            #pragma unroll
            for (int j = 0; j < 4; ++j) acc[mi][j] = zero4;

        // ---- x-phase (independent of h; overlaps group skew) ----
        if constexpr (XB) {
            const unsigned short* xbase = xbp + ((size_t)(b0 + col) * S_ + (size_t)t) * I_ + kwi + (quad << 3);
            #pragma unroll
            for (int kk = 0; kk < 4; ++kk) {
                #pragma unroll
                for (int mi = 0; mi < 4; ++mi) {
                    bf16x8 a = ldb(xbase + (size_t)mi * 16 * S_ * I_ + kk * 32);
                    acc[mi][0] = __builtin_amdgcn_mfma_f32_16x16x32_bf16(a, Bx[0][kk], acc[mi][0], 0, 0, 0);
                    acc[mi][1] = __builtin_amdgcn_mfma_f32_16x16x32_bf16(a, Bx[1][kk], acc[mi][1], 0, 0, 0);
                    acc[mi][2] = __builtin_amdgcn_mfma_f32_16x16x32_bf16(a, Bx[2][kk], acc[mi][2], 0, 0, 0);
                }
            }
        } else {
            const float* xbase = x + ((size_t)(b0 + col) * S_ + (size_t)t) * I_ + kwi + (quad << 3);
            #pragma unroll
            for (int kk = 0; kk < 4; ++kk) {
                #pragma unroll
                for (int mi = 0; mi < 4; ++mi) {
                    const float* p = xbase + (size_t)mi * 16 * S_ * I_ + kk * 32;
                    // nontemporal: x has zero cross-step reuse; keep the
                    // 256MB stream from evicting h/weights out of L3
                    f32x4v f0 = __builtin_nontemporal_load((const f32x4v*)p);
                    f32x4v f1 = __builtin_nontemporal_load((const f32x4v*)(p + 4));
                    U16x8 u;
                    u.u[0] = pack2bf(f0[0], f0[1]);
                    u.u[1] = pack2bf(f0[2], f0[3]);
                    u.u[2] = pack2bf(f1[0], f1[1]);
                    u.u[3] = pack2bf(f1[2], f1[3]);
                    bf16x8 a = u.b;
                    acc[mi][0] = __builtin_amdgcn_mfma_f32_16x16x32_bf16(a, Bx[0][kk], acc[mi][0], 0, 0, 0);
                    acc[mi][1] = __builtin_amdgcn_mfma_f32_16x16x32_bf16(a, Bx[1][kk], acc[mi][1], 0, 0, 0);
                    acc[mi][2] = __builtin_amdgcn_mfma_f32_16x16x32_bf16(a, Bx[2][kk], acc[mi][2], 0, 0, 0);
                }
            }
        }

        // ---- per-lane wait: 64 producer (block,wave) flags >= t ----
        if (t > 0) {
            while (__hip_atomic_load(spin_fp, __ATOMIC_RELAXED, __HIP_MEMORY_SCOPE_AGENT) < (unsigned)t)
                __builtin_amdgcn_s_sleep(1);
            // compiler-only fence: keep the h loads below the spin
            asm volatile("" ::: "memory");
        }

        // ---- h-phase: sc1 loads, explicit 2-deep kk prefetch ----
        const unsigned short* hcur = (t & 1) ? hbufB : hbufA;
        const unsigned short* hrow = hcur + (size_t)(b0 + col) * H_ + kwh + (quad << 3);
        {
            bf16x8 hf[2][4];
            #pragma unroll
            for (int mi = 0; mi < 4; ++mi)
                hf[0][mi] = ldh_dev((const unsigned long long*)(hrow + (size_t)mi * 16 * H_));
            #pragma unroll
            for (int kk = 0; kk < 8; ++kk) {
                if (kk < 7) {
                    #pragma unroll
                    for (int mi = 0; mi < 4; ++mi)
                        hf[(kk + 1) & 1][mi] = ldh_dev((const unsigned long long*)(hrow + (size_t)mi * 16 * H_ + (kk + 1) * 32));
                }
                #pragma unroll
                for (int mi = 0; mi < 4; ++mi) {
                    bf16x8 a = hf[kk & 1][mi];
                    acc[mi][0] = __builtin_amdgcn_mfma_f32_16x16x32_bf16(a, Bh[0][kk], acc[mi][0], 0, 0, 0);
                    acc[mi][1] = __builtin_amdgcn_mfma_f32_16x16x32_bf16(a, Bh[1][kk], acc[mi][1], 0, 0, 0);
                    acc[mi][3] = __builtin_amdgcn_mfma_f32_16x16x32_bf16(a, Bh[2][kk], acc[mi][3], 0, 0, 0);
                }
            }
        }

        // ---- publish partials for the 3 m-slices this wave doesn't own ----
        #pragma unroll
        for (int mi = 0; mi < 4; ++mi) {
            if (mi == w) continue;
            int slot = mi - (mi > w ? 1 : 0);
            float* dst = partial + (size_t)((w * 3 + slot) * 16) * 68;
            #pragma unroll
            for (int j = 0; j < 4; ++j)
                #pragma unroll
                for (int r = 0; r < 4; ++r)
                    dst[((quad << 2) + r) * 68 + j * 16 + col] = acc[mi][j][r];
        }
        __syncthreads();   // A: partials ready; joins the 4 waves' spins ->
                           // all 64 group (block,wave) flags >= t before any
                           // global h store below (ping-pong WAR safety)

        // ---- epilogue: wave w handles batch rows [w*16, w*16+16) ----
        #pragma unroll
        for (int r = 0; r < 4; ++r) {
            float sr = 0.f, sz = 0.f, sia = 0.f, sha = 0.f;
            #pragma unroll
            for (int mi = 0; mi < 4; ++mi)
                if (mi == w) { sr = acc[mi][0][r]; sz = acc[mi][1][r]; sia = acc[mi][2][r]; sha = acc[mi][3][r]; }
            #pragma unroll
            for (int p = 0; p < 4; ++p) {
                if (p == w) continue;
                int slot = w - (w > p ? 1 : 0);
                const float* src = partial + (size_t)(((p * 3 + slot) * 16 + (quad << 2) + r)) * 68 + col;
                sr  += src[0];
                sz  += src[16];
                sia += src[32];
                sha += src[48];
            }
            float rg = 1.f / (1.f + __expf(-(sr + bir)));
            float zg = 1.f / (1.f + __expf(-(sz + biz)));
            float pa = sia + bia + rg * (sha + bnv);
            float e2 = __expf(2.f * pa);
            float ng = 1.f - 2.f / (e2 + 1.f);
            int m = (w << 4) + (quad << 2) + r;
            float hold = h32s[m * 17 + col];
            float hnew = ng + zg * (hold - ng);
            h32s[m * 17 + col] = hnew;
            if (t == S_ - 1) h32g[(size_t)(b0 + m) * H_ + k0 + col] = hnew;
        }
        __syncthreads();   // B: h32s visible; ALSO separates partial reads(t)
                           // from partial publishes(t+1) -- load-bearing WAR

        // ---- packed h store: wave w stores its OWN 16 rows, one 8B sc1
        //      store per lane, then wave-local drain + per-wave flag ----
        {
            unsigned short* hnext = (t & 1) ? hbufA : hbufB;
            const int pm = (w << 4) + (lane >> 2);   // row within [16w,16w+16)
            const int pc = (lane & 3) << 2;          // col quad
            const float* hp = h32s + pm * 17 + pc;
            unsigned long long pkt = (unsigned long long)pack2bf(hp[0], hp[1])
                                   | ((unsigned long long)pack2bf(hp[2], hp[3]) << 32);
            __hip_atomic_store((unsigned long long*)(hnext + (size_t)(b0 + pm) * H_ + k0 + pc),
                               pkt, __ATOMIC_RELAXED, __HIP_MEMORY_SCOPE_AGENT);
            // wave-local drain: this wave's store acked at coherence point
            asm volatile("s_waitcnt vmcnt(0)" ::: "memory");
            if (lane == 0)
                __hip_atomic_store(myflag, (unsigned)(t + 1), __ATOMIC_RELAXED, __HIP_MEMORY_SCOPE_AGENT);
        }
    }
}

// -------- final linear: energies[b] = h_T[b] . wl + bl --------
__global__ __launch_bounds__(256) void final_kernel(const float* __restrict__ h32,
                                                    const float* __restrict__ wl,
                                                    const float* __restrict__ bl,
                                                    float* __restrict__ out) {
    const int b = blockIdx.x;
    float s = 0.f;
    for (int k = threadIdx.x; k < H_; k += 256)
        s += h32[((size_t)b << 10) + k] * wl[k];
    #pragma unroll
    for (int off = 32; off > 0; off >>= 1)
        s += __shfl_down(s, off, 64);
    __shared__ float red[4];
    const int wave = threadIdx.x >> 6;
    const int lane = threadIdx.x & 63;
    if (lane == 0) red[wave] = s;
    __syncthreads();
    if (threadIdx.x == 0)
        out[b] = red[0] + red[1] + red[2] + red[3] + bl[0];
}

extern "C" void kernel_launch(void* const* d_in, const int* in_sizes, int n_in,
                              void* d_out, int out_size, void* d_ws, size_t ws_size,
                              hipStream_t stream) {
    const float* x  = (const float*)d_in[0];
    const float* wi = (const float*)d_in[1];
    const float* wh = (const float*)d_in[2];
    const float* bi = (const float*)d_in[3];
    const float* bn = (const float*)d_in[4];
    const float* wl = (const float*)d_in[5];
    const float* bl = (const float*)d_in[6];
    float* out = (float*)d_out;

    // Workspace layout:
    // [0,1M)      h32g fp32 (256x1024)      [1M,1.5M)  hbA bf16
    // [1.5M,2M)   hbB bf16                  [2M,8M)    whb bf16 (3072x1024)
    // [8M,11M)    wib bf16 (3072x512)       [11M,+64K) flags (256x4 x 64B)
    // [12M,140M)  xb bf16 (256x512x512)     -- only if ws_size >= 140M
    char* ws = (char*)d_ws;
    float*          h32g  = (float*)ws;
    unsigned short* hbA   = (unsigned short*)(ws + (1u << 20));
    unsigned short* hbB   = (unsigned short*)(ws + (1u << 20) + (512u << 10));
    unsigned short* whb   = (unsigned short*)(ws + (2u << 20));
    unsigned short* wib   = (unsigned short*)(ws + (8u << 20));
    unsigned*       flags = (unsigned*)(ws + (11u << 20));
    const bool use_xb = ws_size >= (140ull << 20);
    unsigned short* xbw = use_xb ? (unsigned short*)(ws + (12ull << 20)) : nullptr;

    prep_kernel<<<1024, 256, 0, stream>>>(wh, wi, x, (unsigned*)hbA, (unsigned*)whb,
                                          (unsigned*)wib, flags, (unsigned*)xbw);
    if (use_xb)
        gru_persistent<1><<<256, 256, 0, stream>>>(x, xbw, whb, wib, bi, bn, hbA, hbB, h32g, flags);
    else
        gru_persistent<0><<<256, 256, 0, stream>>>(x, nullptr, whb, wib, bi, bn, hbA, hbB, h32g, flags);
    final_kernel<<<B_, 256, 0, stream>>>(h32g, wl, bl, out);
}